// Round 1
// baseline (327.337 us; speedup 1.0000x reference)
//
#include <hip/hip_runtime.h>

#define NB 256
#define NT 512
#define NI 64
#define NH 256
#define NO 16

typedef __attribute__((ext_vector_type(8))) short short8;
typedef __attribute__((ext_vector_type(8))) __bf16 bf16x8;
typedef __attribute__((ext_vector_type(4))) float f32x4;

__device__ __forceinline__ unsigned short f2bf(float f) {
  unsigned u = __builtin_bit_cast(unsigned, f);
  u += 0x7fffu + ((u >> 16) & 1u);          // round-to-nearest-even
  return (unsigned short)(u >> 16);
}

__device__ __forceinline__ f32x4 mfma16(short8 a, short8 b, f32x4 c) {
  return __builtin_amdgcn_mfma_f32_16x16x32_bf16(
      __builtin_bit_cast(bf16x8, a), __builtin_bit_cast(bf16x8, b), c, 0, 0, 0);
}

// load 8 consecutive f32 (32B-aligned) -> bf16x8 fragment
__device__ __forceinline__ short8 pack8(const float* __restrict__ p) {
  f32x4 lo = *reinterpret_cast<const f32x4*>(p);
  f32x4 hi = *reinterpret_cast<const f32x4*>(p + 4);
  short8 r;
#pragma unroll
  for (int i = 0; i < 4; ++i) {
    r[i]     = (short)f2bf(lo[i]);
    r[i + 4] = (short)f2bf(hi[i]);
  }
  return r;
}

// One block per batch (256 blocks -> 1 per CU). 512 threads = 8 waves.
// Wave w owns hidden columns j in [w*32, w*32+32) as two 16-wide j-tiles.
__global__ __launch_bounds__(512, 2)
void rnn_fused(const float* __restrict__ x,  const float* __restrict__ Wi,
               const float* __restrict__ bi, const float* __restrict__ Wh,
               const float* __restrict__ bh, const float* __restrict__ Wo,
               const float* __restrict__ bo, const float* __restrict__ h0,
               float* __restrict__ dout)
{
  const int b   = blockIdx.x;
  const int tid = threadIdx.x;
  const int w   = tid >> 6;   // wave 0..7
  const int l   = tid & 63;   // lane
  const int lg  = l >> 4;     // 16-lane group 0..3 (k-chunk index)
  const int ll  = l & 15;     // row/col within tile

  // 16-step ring of hidden activations (bf16, per-row XOR-swizzled) + xi window
  __shared__ __align__(16) unsigned short rnnwin[16 * NH]; // 8 KB
  __shared__ __align__(16) float          xi_win[16 * NH]; // 16 KB

  float* outp = dout;                              // [B,T,O]
  float* hidp = dout + (size_t)NB * NT * NO;       // [B,H]
  float* rnnp = hidp + (size_t)NB * NH;            // [B,T,H]

  // ---- persistent W_h2h B-fragments: B[k][n], lane holds n=ll, k=kt*32+lg*8+e ----
  short8 whf[2][8];
#pragma unroll
  for (int nt = 0; nt < 2; ++nt) {
    const int j = w * 32 + nt * 16 + ll;
#pragma unroll
    for (int kt = 0; kt < 8; ++kt)
      whf[nt][kt] = pack8(Wh + (size_t)j * NH + kt * 32 + lg * 8);
  }
  // ---- persistent W_i2h B-fragments ----
  short8 wif[2][2];
#pragma unroll
  for (int nt = 0; nt < 2; ++nt) {
    const int j = w * 32 + nt * 16 + ll;
#pragma unroll
    for (int kt = 0; kt < 2; ++kt)
      wif[nt][kt] = pack8(Wi + (size_t)j * NI + kt * 32 + lg * 8);
  }
  float breg[2];
  breg[0] = bi[w * 32 + ll]      + bh[w * 32 + ll];
  breg[1] = bi[w * 32 + 16 + ll] + bh[w * 32 + 16 + ll];
  const float bout = bo[ll];

  // hidden state: fp32 in registers (uniform across the wave), bf16 A-frags
  float h_reg[2];
  h_reg[0] = h0[w * 32 + ll];
  h_reg[1] = h0[w * 32 + 16 + ll];
  short8 haf[8];
#pragma unroll
  for (int kt = 0; kt < 8; ++kt) haf[kt] = pack8(h0 + kt * 32 + lg * 8);

  const f32x4 cz = {0.f, 0.f, 0.f, 0.f};

  for (int t = 0; t < NT; ++t) {
    const int trow = t & 15;
    if (trow == 0) {
      // ---- output projection of the completed previous window (wave 0) ----
      if (t > 0 && w == 0) {
        f32x4 oacc = cz;
#pragma unroll
        for (int kt = 0; kt < 8; ++kt) {
          const char* ap = (const char*)rnnwin + ll * 512 +
                           ((kt * 64 + lg * 16) ^ (ll << 4));
          short8 af = *reinterpret_cast<const short8*>(ap);
          short8 bf = pack8(Wo + (size_t)ll * NH + kt * 32 + lg * 8);
          oacc = mfma16(af, bf, oacc);
        }
        const int t0 = t - 16;
#pragma unroll
        for (int r = 0; r < 4; ++r) {
          const int tp = lg * 4 + r;
          outp[((size_t)b * NT + t0 + tp) * NO + ll] = oacc[r] + bout;
        }
      }
      // ---- i2h GEMM for window [t, t+16): A rows = 16 timesteps ----
      {
        const float* xp = x + (size_t)b * NT * NI + (size_t)(t + ll) * NI + lg * 8;
        short8 xf0 = pack8(xp);
        short8 xf1 = pack8(xp + 32);
#pragma unroll
        for (int nt = 0; nt < 2; ++nt) {
          f32x4 acc = mfma16(xf0, wif[nt][0], cz);
          acc = mfma16(xf1, wif[nt][1], acc);
#pragma unroll
          for (int r = 0; r < 4; ++r)
            xi_win[(lg * 4 + r) * NH + w * 32 + nt * 16 + ll] = acc[r] + breg[nt];
        }
      }
      __syncthreads();
    }

    // ---- h2h matvec: A rows all hold the same h (broadcast) -> D rows identical
    f32x4 acc0 = mfma16(haf[0], whf[0][0], cz);
    f32x4 acc1 = mfma16(haf[0], whf[1][0], cz);
#pragma unroll
    for (int kt = 1; kt < 8; ++kt) {
      acc0 = mfma16(haf[kt], whf[0][kt], acc0);
      acc1 = mfma16(haf[kt], whf[1][kt], acc1);
    }

    const float xiv0 = xi_win[trow * NH + w * 32 + ll];
    const float xiv1 = xi_win[trow * NH + w * 32 + 16 + ll];
    const float a0 = fminf(fmaxf(h_reg[0] + xiv0 + acc0[0], 0.f), 1.f);
    const float a1 = fminf(fmaxf(h_reg[1] + xiv1 + acc1[0], 0.f), 1.f);
    h_reg[0] = a0;
    h_reg[1] = a1;

    if (l < 16) {
      const int base = trow * 512;
      const int o0 = (2 * (w * 32 + ll))      ^ (trow << 4);
      const int o1 = (2 * (w * 32 + 16 + ll)) ^ (trow << 4);
      rnnwin[(base + o0) >> 1] = f2bf(a0);
      rnnwin[(base + o1) >> 1] = f2bf(a1);
      float* rp = rnnp + ((size_t)b * NT + t) * NH + w * 32 + ll;
      rp[0]  = a0;
      rp[16] = a1;
    }
    __syncthreads();

    // A-fragments of h_t for the next step (broadcast within 16-lane groups)
#pragma unroll
    for (int kt = 0; kt < 8; ++kt) {
      const char* ap = (const char*)rnnwin + trow * 512 +
                       ((kt * 64 + lg * 16) ^ (trow << 4));
      haf[kt] = *reinterpret_cast<const short8*>(ap);
    }
  }

  // ---- final window's output projection ----
  if (w == 0) {
    f32x4 oacc = cz;
#pragma unroll
    for (int kt = 0; kt < 8; ++kt) {
      const char* ap = (const char*)rnnwin + ll * 512 +
                       ((kt * 64 + lg * 16) ^ (ll << 4));
      short8 af = *reinterpret_cast<const short8*>(ap);
      short8 bf = pack8(Wo + (size_t)ll * NH + kt * 32 + lg * 8);
      oacc = mfma16(af, bf, oacc);
    }
#pragma unroll
    for (int r = 0; r < 4; ++r) {
      const int tp = lg * 4 + r;
      outp[((size_t)b * NT + (NT - 16) + tp) * NO + ll] = oacc[r] + bout;
    }
  }
  // ---- hidden = h after T steps ----
  if (l < 16) {
    hidp[(size_t)b * NH + w * 32 + ll]      = h_reg[0];
    hidp[(size_t)b * NH + w * 32 + 16 + ll] = h_reg[1];
  }
}

extern "C" void kernel_launch(void* const* d_in, const int* in_sizes, int n_in,
                              void* d_out, int out_size, void* d_ws, size_t ws_size,
                              hipStream_t stream) {
  const float* x  = (const float*)d_in[0];
  const float* Wi = (const float*)d_in[1];
  const float* bi = (const float*)d_in[2];
  const float* Wh = (const float*)d_in[3];
  const float* bh = (const float*)d_in[4];
  const float* Wo = (const float*)d_in[5];
  const float* bo = (const float*)d_in[6];
  const float* h0 = (const float*)d_in[7];
  rnn_fused<<<dim3(NB), dim3(512), 0, stream>>>(x, Wi, bi, Wh, bh, Wo, bo, h0,
                                                (float*)d_out);
}

// Round 2
// 283.534 us; speedup vs baseline: 1.1545x; 1.1545x over previous
//
#include <hip/hip_runtime.h>

#define NB 256
#define NT 512
#define NI 64
#define NH 256
#define NO 16

typedef __attribute__((ext_vector_type(8))) short short8;
typedef __attribute__((ext_vector_type(8))) __bf16 bf16x8;
typedef __attribute__((ext_vector_type(4))) float f32x4;

__device__ __forceinline__ unsigned short f2bf(float f) {
  unsigned u = __builtin_bit_cast(unsigned, f);
  u += 0x7fffu + ((u >> 16) & 1u);          // round-to-nearest-even
  return (unsigned short)(u >> 16);
}

__device__ __forceinline__ f32x4 mfma16(short8 a, short8 b, f32x4 c) {
  return __builtin_amdgcn_mfma_f32_16x16x32_bf16(
      __builtin_bit_cast(bf16x8, a), __builtin_bit_cast(bf16x8, b), c, 0, 0, 0);
}

__device__ __forceinline__ short8 pack8v(f32x4 lo, f32x4 hi) {
  short8 r;
#pragma unroll
  for (int i = 0; i < 4; ++i) {
    r[i]     = (short)f2bf(lo[i]);
    r[i + 4] = (short)f2bf(hi[i]);
  }
  return r;
}

__device__ __forceinline__ short8 pack8(const float* __restrict__ p) {
  return pack8v(*reinterpret_cast<const f32x4*>(p),
                *reinterpret_cast<const f32x4*>(p + 4));
}

// LDS-only barrier: drain our DS ops, sync, pin following memory ops after.
// (Raw s_barrier does NOT drain vmcnt -> global stores/loads stay in flight.)
__device__ __forceinline__ void step_barrier() {
  asm volatile("s_waitcnt lgkmcnt(0)" ::: "memory");
  __builtin_amdgcn_s_barrier();
  asm volatile("" ::: "memory");
}

// One block per batch (256 blocks -> 1 per CU). 512 threads = 8 waves.
// Wave w owns hidden columns j in [w*32, w*32+32) as two 16-wide j-tiles.
__global__ __launch_bounds__(512, 2)
void rnn_fused(const float* __restrict__ x,  const float* __restrict__ Wi,
               const float* __restrict__ bi, const float* __restrict__ Wh,
               const float* __restrict__ bh, const float* __restrict__ Wo,
               const float* __restrict__ bo, const float* __restrict__ h0,
               float* __restrict__ dout)
{
  const int b   = blockIdx.x;
  const int tid = threadIdx.x;
  const int w   = tid >> 6;   // wave 0..7
  const int l   = tid & 63;   // lane
  const int lg  = l >> 4;     // 16-lane group 0..3 (k-chunk index)
  const int ll  = l & 15;     // row/col within tile

  // 16-step ring of hidden activations (bf16, per-row XOR-swizzled) + xi window
  __shared__ __align__(16) unsigned short rnnwin[16 * NH]; // 8 KB
  __shared__ __align__(16) float          xi_win[16 * NH]; // 16 KB

  float* outp = dout;                              // [B,T,O]
  float* hidp = dout + (size_t)NB * NT * NO;       // [B,H]
  float* rnnp = hidp + (size_t)NB * NH;            // [B,T,H]

  // ---- persistent W_h2h B-fragments: B[k][n], lane holds n=ll, k=kt*32+lg*8+e ----
  short8 whf[2][8];
#pragma unroll
  for (int nt = 0; nt < 2; ++nt) {
    const int j = w * 32 + nt * 16 + ll;
#pragma unroll
    for (int kt = 0; kt < 8; ++kt)
      whf[nt][kt] = pack8(Wh + (size_t)j * NH + kt * 32 + lg * 8);
  }
  // ---- persistent W_i2h B-fragments ----
  short8 wif[2][2];
#pragma unroll
  for (int nt = 0; nt < 2; ++nt) {
    const int j = w * 32 + nt * 16 + ll;
#pragma unroll
    for (int kt = 0; kt < 2; ++kt)
      wif[nt][kt] = pack8(Wi + (size_t)j * NI + kt * 32 + lg * 8);
  }
  // ---- persistent W_out B-fragments (used by wave 0 only) ----
  short8 wof[8];
#pragma unroll
  for (int kt = 0; kt < 8; ++kt)
    wof[kt] = pack8(Wo + (size_t)ll * NH + kt * 32 + lg * 8);

  float breg[2];
  breg[0] = bi[w * 32 + ll]      + bh[w * 32 + ll];
  breg[1] = bi[w * 32 + 16 + ll] + bh[w * 32 + 16 + ll];
  const float bout = bo[ll];

  // hidden state: fp32 in registers, bf16 A-frags (broadcast rows)
  float h_reg[2];
  h_reg[0] = h0[w * 32 + ll];
  h_reg[1] = h0[w * 32 + 16 + ll];
  short8 haf[8];
#pragma unroll
  for (int kt = 0; kt < 8; ++kt) haf[kt] = pack8(h0 + kt * 32 + lg * 8);

  // ---- x prefetch (one window ahead), 16 floats/thread in registers ----
  f32x4 xpre[4];
  {
    const float* xp = x + (size_t)b * NT * NI + (size_t)ll * NI + lg * 8;
    xpre[0] = *reinterpret_cast<const f32x4*>(xp);
    xpre[1] = *reinterpret_cast<const f32x4*>(xp + 4);
    xpre[2] = *reinterpret_cast<const f32x4*>(xp + 32);
    xpre[3] = *reinterpret_cast<const f32x4*>(xp + 36);
  }

  const f32x4 cz = {0.f, 0.f, 0.f, 0.f};

  for (int t = 0; t < NT; ++t) {
    const int trow = t & 15;
    if (trow == 0) {
      // ---- output projection of the completed previous window (wave 0) ----
      if (t > 0 && w == 0) {
        f32x4 oacc = cz;
#pragma unroll
        for (int kt = 0; kt < 8; ++kt) {
          const char* ap = (const char*)rnnwin + ll * 512 +
                           ((kt * 64 + lg * 16) ^ (ll << 4));
          short8 af = *reinterpret_cast<const short8*>(ap);
          oacc = mfma16(af, wof[kt], oacc);
        }
        const int t0 = t - 16;
#pragma unroll
        for (int r = 0; r < 4; ++r) {
          const int tp = lg * 4 + r;
          outp[((size_t)b * NT + t0 + tp) * NO + ll] = oacc[r] + bout;
        }
      }
      // ---- i2h GEMM for window [t, t+16) from prefetched registers ----
      {
        short8 xf0 = pack8v(xpre[0], xpre[1]);
        short8 xf1 = pack8v(xpre[2], xpre[3]);
#pragma unroll
        for (int nt = 0; nt < 2; ++nt) {
          f32x4 acc = mfma16(xf0, wif[nt][0], cz);
          acc = mfma16(xf1, wif[nt][1], acc);
#pragma unroll
          for (int r = 0; r < 4; ++r)
            xi_win[(lg * 4 + r) * NH + w * 32 + nt * 16 + ll] = acc[r] + breg[nt];
        }
      }
      // ---- issue next window's x loads (in flight across 16 steps) ----
      if (t + 16 < NT) {
        const float* xp = x + (size_t)b * NT * NI + (size_t)(t + 16 + ll) * NI + lg * 8;
        xpre[0] = *reinterpret_cast<const f32x4*>(xp);
        xpre[1] = *reinterpret_cast<const f32x4*>(xp + 4);
        xpre[2] = *reinterpret_cast<const f32x4*>(xp + 32);
        xpre[3] = *reinterpret_cast<const f32x4*>(xp + 36);
      }
      step_barrier();
    }

    // ---- h2h matvec: 4 independent 4-deep MFMA chains (rows broadcast) ----
    f32x4 a0a = mfma16(haf[0], whf[0][0], cz);
    f32x4 a0b = mfma16(haf[4], whf[0][4], cz);
    f32x4 a1a = mfma16(haf[0], whf[1][0], cz);
    f32x4 a1b = mfma16(haf[4], whf[1][4], cz);
#pragma unroll
    for (int kt = 1; kt < 4; ++kt) {
      a0a = mfma16(haf[kt],     whf[0][kt],     a0a);
      a0b = mfma16(haf[kt + 4], whf[0][kt + 4], a0b);
      a1a = mfma16(haf[kt],     whf[1][kt],     a1a);
      a1b = mfma16(haf[kt + 4], whf[1][kt + 4], a1b);
    }

    const float xiv0 = xi_win[trow * NH + w * 32 + ll];
    const float xiv1 = xi_win[trow * NH + w * 32 + 16 + ll];
    const float a0 = fminf(fmaxf(h_reg[0] + xiv0 + (a0a[0] + a0b[0]), 0.f), 1.f);
    const float a1 = fminf(fmaxf(h_reg[1] + xiv1 + (a1a[0] + a1b[0]), 0.f), 1.f);
    h_reg[0] = a0;
    h_reg[1] = a1;

    if (l < 16) {
      const int base = trow * 512;
      const int o0 = (2 * (w * 32 + ll))      ^ (trow << 4);
      const int o1 = (2 * (w * 32 + 16 + ll)) ^ (trow << 4);
      rnnwin[(base + o0) >> 1] = f2bf(a0);
      rnnwin[(base + o1) >> 1] = f2bf(a1);
    }
    // rnn_out store: lanes 0..31 -> one contiguous 128B store per wave,
    // stays in flight (raw barrier never drains vmcnt)
    if (l < 32)
      rnnp[((size_t)b * NT + t) * NH + w * 32 + l] = (l < 16) ? a0 : a1;

    step_barrier();

    // A-fragments of h_t for the next step (broadcast within 16-lane groups)
#pragma unroll
    for (int kt = 0; kt < 8; ++kt) {
      const char* ap = (const char*)rnnwin + trow * 512 +
                       ((kt * 64 + lg * 16) ^ (trow << 4));
      haf[kt] = *reinterpret_cast<const short8*>(ap);
    }
  }

  // ---- final window's output projection ----
  if (w == 0) {
    f32x4 oacc = cz;
#pragma unroll
    for (int kt = 0; kt < 8; ++kt) {
      const char* ap = (const char*)rnnwin + ll * 512 +
                       ((kt * 64 + lg * 16) ^ (ll << 4));
      short8 af = *reinterpret_cast<const short8*>(ap);
      oacc = mfma16(af, wof[kt], oacc);
    }
#pragma unroll
    for (int r = 0; r < 4; ++r) {
      const int tp = lg * 4 + r;
      outp[((size_t)b * NT + (NT - 16) + tp) * NO + ll] = oacc[r] + bout;
    }
  }
  // ---- hidden = h after T steps ----
  if (l < 16) {
    hidp[(size_t)b * NH + w * 32 + ll]      = h_reg[0];
    hidp[(size_t)b * NH + w * 32 + 16 + ll] = h_reg[1];
  }
}

extern "C" void kernel_launch(void* const* d_in, const int* in_sizes, int n_in,
                              void* d_out, int out_size, void* d_ws, size_t ws_size,
                              hipStream_t stream) {
  const float* x  = (const float*)d_in[0];
  const float* Wi = (const float*)d_in[1];
  const float* bi = (const float*)d_in[2];
  const float* Wh = (const float*)d_in[3];
  const float* bh = (const float*)d_in[4];
  const float* Wo = (const float*)d_in[5];
  const float* bo = (const float*)d_in[6];
  const float* h0 = (const float*)d_in[7];
  rnn_fused<<<dim3(NB), dim3(512), 0, stream>>>(x, Wi, bi, Wh, bh, Wo, bo, h0,
                                                (float*)d_out);
}